// Round 3
// baseline (119.197 us; speedup 1.0000x reference)
//
#include <hip/hip_runtime.h>
#include <hip/hip_fp16.h>

#define IN_DIM 16
#define HID 8
#define C1   2.8853900817779268f   // 2*log2(e): folded into W1/b1 so tanh uses bare v_exp_f32
#define NL2E 1.4426950408889634f   // log2(e):   folded (negated) into W2/b2 for bare-exp2 sigmoid

typedef int   v4i __attribute__((ext_vector_type(4)));
typedef float v4f __attribute__((ext_vector_type(4)));

// Bare v_exp_f32 (2^x). NOTE: __exp2f collides with a glibc math.h macro on this
// toolchain -> use the amdgcn builtin directly.
__device__ __forceinline__ float exp2_raw(float x) { return __builtin_amdgcn_exp2f(x); }

// Per-node precompute, packed fp16, PRE-SCALED by 2*log2(e):
//   uv[n][0..7]  = 2*log2e*(x[n]·W1[0:16] + b1)   ("x[col]" half, bias folded here)
//   uv[n][8..15] = 2*log2e*(x[n]·W1[16:32])       ("x[row]" half)
// tanh(z) = 1 - 2/(exp2(zs)+1) with zs = u+v already scaled -> no mul before v_exp_f32.
// Total uv = 100K × 32 B = 3.2 MB → resident in each XCD's 4 MB L2.
__global__ __launch_bounds__(256) void node_pre(
    const float* __restrict__ x, const float* __restrict__ W1,
    const float* __restrict__ b1, __half* __restrict__ uv, int n_nodes)
{
    __shared__ float sW[2 * IN_DIM * HID];
    __shared__ float sb[HID];
    int t = threadIdx.x;
    if (t < 2 * IN_DIM * HID) sW[t] = W1[t] * C1;   // fold scale into weights (free)
    if (t < HID) sb[t] = b1[t] * C1;
    __syncthreads();
    int n = blockIdx.x * 256 + t;
    if (n >= n_nodes) return;

    const float4* xp = (const float4*)(x + (size_t)n * IN_DIM);
    float xr[IN_DIM];
    float4 a;
    a = xp[0]; xr[0]=a.x;  xr[1]=a.y;  xr[2]=a.z;  xr[3]=a.w;
    a = xp[1]; xr[4]=a.x;  xr[5]=a.y;  xr[6]=a.z;  xr[7]=a.w;
    a = xp[2]; xr[8]=a.x;  xr[9]=a.y;  xr[10]=a.z; xr[11]=a.w;
    a = xp[3]; xr[12]=a.x; xr[13]=a.y; xr[14]=a.z; xr[15]=a.w;

    float au[HID], av[HID];
    #pragma unroll
    for (int j = 0; j < HID; j++) { au[j] = sb[j]; av[j] = 0.0f; }
    #pragma unroll
    for (int k = 0; k < IN_DIM; k++) {
        #pragma unroll
        for (int j = 0; j < HID; j++) {
            au[j] = fmaf(xr[k], sW[k * HID + j], au[j]);           // sW wave-uniform -> LDS broadcast
            av[j] = fmaf(xr[k], sW[(IN_DIM + k) * HID + j], av[j]);
        }
    }
    union { __half2 h[4]; float4 f; } pu, pv;
    #pragma unroll
    for (int i = 0; i < 4; i++) {
        pu.h[i] = __floats2half2_rn(au[2*i], au[2*i+1]);
        pv.h[i] = __floats2half2_rn(av[2*i], av[2*i+1]);
    }
    float4* o = (float4*)(uv + (size_t)n * 16);
    o[0] = pu.f;   // u half
    o[1] = pv.f;   // v half
}

// u,v pre-scaled by 2*log2e; sw2/sb2 pre-scaled by -log2e.
// tanh(z) = 1 - 2/(exp2(u+v)+1); sigmoid = 1/(1+exp2(s)) with s = -log2e*(t·W2+b2).
__device__ __forceinline__ float edge_eval(float4 uf, float4 vf,
                                           const float* sw2, float sb2)
{
    union { float4 f; __half2 h[4]; } U, V;
    U.f = uf; V.f = vf;
    float s = sb2;
    #pragma unroll
    for (int i = 0; i < 4; i++) {
        float2 a = __half22float2(U.h[i]);
        float2 b = __half22float2(V.h[i]);
        float e0 = exp2_raw(a.x + b.x);                      // bare v_exp_f32
        float e1 = exp2_raw(a.y + b.y);
        float t0 = 1.0f - 2.0f * __builtin_amdgcn_rcpf(e0 + 1.0f);
        float t1 = 1.0f - 2.0f * __builtin_amdgcn_rcpf(e1 + 1.0f);
        s = fmaf(t0, sw2[2*i],   s);
        s = fmaf(t1, sw2[2*i+1], s);
    }
    return __builtin_amdgcn_rcpf(1.0f + exp2_raw(s));
}

// 8 L1-bypassing (sc0) 16 B gathers, trailing vmcnt(0) — used only on the tail path.
__device__ __forceinline__ void gather8_sc0(
    const float4* a0, const float4* a1, const float4* a2, const float4* a3,
    const float4* a4, const float4* a5, const float4* a6, const float4* a7,
    float4& r0, float4& r1, float4& r2, float4& r3,
    float4& r4, float4& r5, float4& r6, float4& r7)
{
    asm volatile(
        "global_load_dwordx4 %0, %8, off sc0\n\t"
        "global_load_dwordx4 %1, %9, off sc0\n\t"
        "global_load_dwordx4 %2, %10, off sc0\n\t"
        "global_load_dwordx4 %3, %11, off sc0\n\t"
        "global_load_dwordx4 %4, %12, off sc0\n\t"
        "global_load_dwordx4 %5, %13, off sc0\n\t"
        "global_load_dwordx4 %6, %14, off sc0\n\t"
        "global_load_dwordx4 %7, %15, off sc0\n\t"
        "s_waitcnt vmcnt(0)"
        : "=&v"(r0), "=&v"(r1), "=&v"(r2), "=&v"(r3),
          "=&v"(r4), "=&v"(r5), "=&v"(r6), "=&v"(r7)
        : "v"(a0), "v"(a1), "v"(a2), "v"(a3),
          "v"(a4), "v"(a5), "v"(a6), "v"(a7)
        : "memory");
}

__device__ __forceinline__ void edge_scalar(long e, const int* idx, long n_edges,
    const float4* uvp, const float* sw2, float lb2, float* __restrict__ out)
{
    int r = idx[e];
    int c = idx[n_edges + e];
    out[e] = edge_eval(uvp[2*(size_t)c], uvp[2*(size_t)r + 1], sw2, lb2);
}

// 8 edges/thread in two 4-edge groups. All 16 gathers issued back-to-back in ONE
// asm block (no internal waitcnt); then counted waits:
//   s_waitcnt vmcnt(8)  -> group A resident, compute A while B's 8 loads in flight
//   s_waitcnt vmcnt(0)  -> group B resident, compute B
// Ordering discipline (guide rule #18): tied-register waitcnts don't compile for
// multi-reg (indirect) operands, so each bare waitcnt is followed IMMEDIATELY by
// __builtin_amdgcn_sched_barrier(0), which pins the consuming VALU below the wait.
// Data-dependence on the load-asm outputs already pins consumers below the loads.
__global__ __launch_bounds__(256) void edge_k(
    const int* __restrict__ idx, const __half* __restrict__ uv,
    const float* __restrict__ W2, const float* __restrict__ b2,
    float* __restrict__ out, int n_edges)
{
    __shared__ float sw2[HID];
    __shared__ float sb2;
    int t = threadIdx.x;
    if (t < HID) sw2[t] = W2[t] * -NL2E;   // fold -log2e into W2 (free)
    if (t == 0) sb2 = b2[0] * -NL2E;
    __syncthreads();
    float lb2 = sb2;

    const float4* uvp = (const float4*)uv;  // 16 B granules; node n = granule 2n (u), 2n+1 (v)
    long base = (long)blockIdx.x * 2048;
    long eA = base + (long)t * 4;           // group A: [base, base+1024) — coalesced idx/out
    long eB = eA + 1024;                    // group B: [base+1024, base+2048)

    if (eB + 4 <= n_edges) {
        // streaming (non-temporal) idx loads: don't evict the uv working set from L2
        v4i rA = __builtin_nontemporal_load((const v4i*)(idx + eA));
        v4i cA = __builtin_nontemporal_load((const v4i*)(idx + n_edges + eA));
        v4i rB = __builtin_nontemporal_load((const v4i*)(idx + eB));
        v4i cB = __builtin_nontemporal_load((const v4i*)(idx + n_edges + eB));

        float4 uA0, uA1, uA2, uA3, wA0, wA1, wA2, wA3;
        float4 uB0, uB1, uB2, uB3, wB0, wB1, wB2, wB3;
        asm volatile(
            "global_load_dwordx4 %0, %16, off sc0\n\t"
            "global_load_dwordx4 %1, %17, off sc0\n\t"
            "global_load_dwordx4 %2, %18, off sc0\n\t"
            "global_load_dwordx4 %3, %19, off sc0\n\t"
            "global_load_dwordx4 %4, %20, off sc0\n\t"
            "global_load_dwordx4 %5, %21, off sc0\n\t"
            "global_load_dwordx4 %6, %22, off sc0\n\t"
            "global_load_dwordx4 %7, %23, off sc0\n\t"
            "global_load_dwordx4 %8, %24, off sc0\n\t"
            "global_load_dwordx4 %9, %25, off sc0\n\t"
            "global_load_dwordx4 %10, %26, off sc0\n\t"
            "global_load_dwordx4 %11, %27, off sc0\n\t"
            "global_load_dwordx4 %12, %28, off sc0\n\t"
            "global_load_dwordx4 %13, %29, off sc0\n\t"
            "global_load_dwordx4 %14, %30, off sc0\n\t"
            "global_load_dwordx4 %15, %31, off sc0"
            : "=&v"(uA0), "=&v"(uA1), "=&v"(uA2), "=&v"(uA3),
              "=&v"(wA0), "=&v"(wA1), "=&v"(wA2), "=&v"(wA3),
              "=&v"(uB0), "=&v"(uB1), "=&v"(uB2), "=&v"(uB3),
              "=&v"(wB0), "=&v"(wB1), "=&v"(wB2), "=&v"(wB3)
            : "v"(uvp + 2*(size_t)cA.x),     "v"(uvp + 2*(size_t)cA.y),
              "v"(uvp + 2*(size_t)cA.z),     "v"(uvp + 2*(size_t)cA.w),
              "v"(uvp + 2*(size_t)rA.x + 1), "v"(uvp + 2*(size_t)rA.y + 1),
              "v"(uvp + 2*(size_t)rA.z + 1), "v"(uvp + 2*(size_t)rA.w + 1),
              "v"(uvp + 2*(size_t)cB.x),     "v"(uvp + 2*(size_t)cB.y),
              "v"(uvp + 2*(size_t)cB.z),     "v"(uvp + 2*(size_t)cB.w),
              "v"(uvp + 2*(size_t)rB.x + 1), "v"(uvp + 2*(size_t)rB.y + 1),
              "v"(uvp + 2*(size_t)rB.z + 1), "v"(uvp + 2*(size_t)rB.w + 1)
            : "memory");

        // group A resident; B's 8 loads still in flight under the compute below
        asm volatile("s_waitcnt vmcnt(8)" ::: "memory");
        __builtin_amdgcn_sched_barrier(0);   // pin A-consumers below the wait (rule #18)

        v4f ra;
        ra.x = edge_eval(uA0, wA0, sw2, lb2);
        ra.y = edge_eval(uA1, wA1, sw2, lb2);
        ra.z = edge_eval(uA2, wA2, sw2, lb2);
        ra.w = edge_eval(uA3, wA3, sw2, lb2);

        asm volatile("s_waitcnt vmcnt(0)" ::: "memory");
        __builtin_amdgcn_sched_barrier(0);   // pin B-consumers below the wait

        v4f rb;
        rb.x = edge_eval(uB0, wB0, sw2, lb2);
        rb.y = edge_eval(uB1, wB1, sw2, lb2);
        rb.z = edge_eval(uB2, wB2, sw2, lb2);
        rb.w = edge_eval(uB3, wB3, sw2, lb2);

        __builtin_nontemporal_store(ra, (v4f*)(out + eA));
        __builtin_nontemporal_store(rb, (v4f*)(out + eB));
    } else {
        // Tail: keep group A vectorized if it fits (the half-block at the end),
        // scalar-catch everything else.
        if (eA + 4 <= n_edges) {
            v4i rows = __builtin_nontemporal_load((const v4i*)(idx + eA));
            v4i cols = __builtin_nontemporal_load((const v4i*)(idx + n_edges + eA));
            float4 u0, u1, u2, u3, w0, w1, w2, w3;
            gather8_sc0(uvp + 2*(size_t)cols.x,     uvp + 2*(size_t)cols.y,
                        uvp + 2*(size_t)cols.z,     uvp + 2*(size_t)cols.w,
                        uvp + 2*(size_t)rows.x + 1, uvp + 2*(size_t)rows.y + 1,
                        uvp + 2*(size_t)rows.z + 1, uvp + 2*(size_t)rows.w + 1,
                        u0, u1, u2, u3, w0, w1, w2, w3);
            v4f r;
            r.x = edge_eval(u0, w0, sw2, lb2);
            r.y = edge_eval(u1, w1, sw2, lb2);
            r.z = edge_eval(u2, w2, sw2, lb2);
            r.w = edge_eval(u3, w3, sw2, lb2);
            __builtin_nontemporal_store(r, (v4f*)(out + eA));
        } else {
            for (long e = eA; e < n_edges && e < eA + 4; ++e)
                edge_scalar(e, idx, n_edges, uvp, sw2, lb2, out);
        }
        for (long e = eB; e < n_edges && e < eB + 4; ++e)
            edge_scalar(e, idx, n_edges, uvp, sw2, lb2, out);
    }
}

extern "C" void kernel_launch(void* const* d_in, const int* in_sizes, int n_in,
                              void* d_out, int out_size, void* d_ws, size_t ws_size,
                              hipStream_t stream) {
    const float* x  = (const float*)d_in[0];
    const int*   idx = (const int*)d_in[1];
    const float* W1 = (const float*)d_in[2];
    const float* b1 = (const float*)d_in[3];
    const float* W2 = (const float*)d_in[4];
    const float* b2 = (const float*)d_in[5];
    float* out = (float*)d_out;

    int n_nodes = in_sizes[0] / IN_DIM;
    int n_edges = in_sizes[1] / 2;

    __half* uv = (__half*)d_ws;   // n_nodes*16 halfs = 3.2 MB (ws must be >= 3.2 MB)

    node_pre<<<(n_nodes + 255) / 256, 256, 0, stream>>>(x, W1, b1, uv, n_nodes);
    int epb = 256 * 8;
    edge_k<<<(n_edges + epb - 1) / epb, 256, 0, stream>>>(idx, uv, W2, b2, out, n_edges);
}